// Round 1
// baseline (225.071 us; speedup 1.0000x reference)
//
#include <hip/hip_runtime.h>

// SSIM loss, fused single-pass tile kernel + tiny fp64 finalize.
// Images: 16*3 = 48 independent 512x512 fp32 planes, 11x11 separable
// (UNNORMALIZED, faithful to reference) Gaussian, zero padding (pad=5).

#define IMG   512
#define NIMG  48
#define TW    32
#define TH    32
#define PADR  5
#define PW    (TW + 2*PADR)   // 42
#define PH    (TH + 2*PADR)   // 42
#define TILES_X (IMG / TW)    // 16
#define TILES_Y (IMG / TH)    // 16
#define NBLOCKS (NIMG * TILES_X * TILES_Y)  // 12288

__global__ __launch_bounds__(256) void ssim_tile_kernel(
    const float* __restrict__ img1, const float* __restrict__ img2,
    float* __restrict__ partials)
{
    __shared__ float s1[PH][PW];          // 7056 B
    __shared__ float s2[PH][PW];          // 7056 B
    __shared__ float sh[5][PH][TW];       // 26880 B  (mu1,mu2,x11,x22,x12 after h-pass)
    __shared__ float s_part[4];

    const int tid = threadIdx.x;
    const int tx0 = blockIdx.x * TW - PADR;
    const int ty0 = blockIdx.y * TH - PADR;
    const float* __restrict__ p1 = img1 + (size_t)blockIdx.z * (IMG * IMG);
    const float* __restrict__ p2 = img2 + (size_t)blockIdx.z * (IMG * IMG);

    // ---- load padded input tiles (zero pad outside image) ----
    for (int i = tid; i < PH * PW; i += 256) {
        int r = i / PW, c = i - r * PW;
        int gr = ty0 + r, gc = tx0 + c;
        bool ok = ((unsigned)gr < IMG) && ((unsigned)gc < IMG);
        int gi = gr * IMG + gc;
        s1[r][c] = ok ? p1[gi] : 0.0f;
        s2[r][c] = ok ? p2[gi] : 0.0f;
    }

    // Gaussian taps, fp32 formula faithful to reference (unnormalized)
    float g[11];
#pragma unroll
    for (int k = 0; k < 11; ++k) {
        float d = (float)(k - 5);
        g[k] = expf(-(d * d) * (1.0f / 4.5f));   // 2*sigma^2 = 4.5
    }

    __syncthreads();

    // ---- horizontal pass: 5 channels, rows 0..41, output cols 0..31 ----
    for (int i = tid; i < PH * TW; i += 256) {
        int r = i >> 5, c = i & 31;
        float a1 = 0.f, a2 = 0.f, a11 = 0.f, a22 = 0.f, a12 = 0.f;
#pragma unroll
        for (int k = 0; k < 11; ++k) {
            float v1 = s1[r][c + k];
            float v2 = s2[r][c + k];
            float w = g[k];
            a1  += w * v1;
            a2  += w * v2;
            a11 += w * v1 * v1;
            a22 += w * v2 * v2;
            a12 += w * v1 * v2;
        }
        sh[0][r][c] = a1;  sh[1][r][c] = a2;
        sh[2][r][c] = a11; sh[3][r][c] = a22; sh[4][r][c] = a12;
    }
    __syncthreads();

    // ---- vertical pass: thread -> (col, 4-row segment), sliding reuse ----
    const int col = tid & 31;
    const int r0  = (tid >> 5) * 4;   // 0..28

    float acc[5][4];
#pragma unroll
    for (int ch = 0; ch < 5; ++ch)
#pragma unroll
        for (int i = 0; i < 4; ++i) acc[ch][i] = 0.f;

#pragma unroll
    for (int j = 0; j < 14; ++j) {
        float h0 = sh[0][r0 + j][col];
        float h1 = sh[1][r0 + j][col];
        float h2 = sh[2][r0 + j][col];
        float h3 = sh[3][r0 + j][col];
        float h4 = sh[4][r0 + j][col];
#pragma unroll
        for (int i = 0; i < 4; ++i) {
            int k = j - i;
            if (k >= 0 && k < 11) {
                float w = g[k];
                acc[0][i] += w * h0;
                acc[1][i] += w * h1;
                acc[2][i] += w * h2;
                acc[3][i] += w * h3;
                acc[4][i] += w * h4;
            }
        }
    }

    // ---- SSIM map + local sum ----
    const float C1 = 1.0e-4f;   // 0.01^2
    const float C2 = 9.0e-4f;   // 0.03^2
    float local = 0.f;
#pragma unroll
    for (int i = 0; i < 4; ++i) {
        float mu1 = acc[0][i], mu2 = acc[1][i];
        float x11 = acc[2][i], x22 = acc[3][i], x12 = acc[4][i];
        float mu1s = mu1 * mu1, mu2s = mu2 * mu2, m12 = mu1 * mu2;
        float sg1 = x11 - mu1s, sg2 = x22 - mu2s, sg12 = x12 - m12;
        float num = (2.f * m12 + C1) * (2.f * sg12 + C2);
        float den = (mu1s + mu2s + C1) * (sg1 + sg2 + C2);
        local += num / den;
    }

    // ---- block reduction (fp32 within block is exact enough: ~1024 O(1) vals)
#pragma unroll
    for (int off = 32; off > 0; off >>= 1)
        local += __shfl_down(local, off, 64);
    if ((tid & 63) == 0) s_part[tid >> 6] = local;
    __syncthreads();
    if (tid == 0) {
        int bidx = (blockIdx.z * gridDim.y + blockIdx.y) * gridDim.x + blockIdx.x;
        partials[bidx] = s_part[0] + s_part[1] + s_part[2] + s_part[3];
    }
}

__global__ __launch_bounds__(256) void ssim_final_kernel(
    const float* __restrict__ partials, float* __restrict__ out)
{
    __shared__ double sp[4];
    double acc = 0.0;
    for (int i = threadIdx.x; i < NBLOCKS; i += 256)
        acc += (double)partials[i];
#pragma unroll
    for (int off = 32; off > 0; off >>= 1)
        acc += __shfl_down(acc, off, 64);
    if ((threadIdx.x & 63) == 0) sp[threadIdx.x >> 6] = acc;
    __syncthreads();
    if (threadIdx.x == 0) {
        double total = sp[0] + sp[1] + sp[2] + sp[3];
        out[0] = (float)(1.0 - total / (double)((size_t)NIMG * IMG * IMG));
    }
}

extern "C" void kernel_launch(void* const* d_in, const int* in_sizes, int n_in,
                              void* d_out, int out_size, void* d_ws, size_t ws_size,
                              hipStream_t stream) {
    const float* img1 = (const float*)d_in[0];
    const float* img2 = (const float*)d_in[1];
    float* out = (float*)d_out;
    float* partials = (float*)d_ws;   // NBLOCKS floats = 48 KiB, fully rewritten every call

    dim3 grid(TILES_X, TILES_Y, NIMG);
    ssim_tile_kernel<<<grid, dim3(256), 0, stream>>>(img1, img2, partials);
    ssim_final_kernel<<<1, dim3(256), 0, stream>>>(partials, out);
}

// Round 2
// 199.888 us; speedup vs baseline: 1.1260x; 1.1260x over previous
//
#include <hip/hip_runtime.h>

// SSIM loss — fused separable-conv tile kernel, v2.
// Changes vs v1: register-sliding h-pass (products computed once, b128 LDS
// reads), channel-split (2 groups) so the staging buffer is 3 channels ->
// 31.7KB LDS -> 5 blocks/CU, transposed staging so v-pass reads are b128.

#define IMG   512
#define NIMG  48
#define TW    32
#define TH    32
#define PH    42          // TH + 10
#define PWS   44          // padded LDS row stride (42 used)
#define TILES 16
#define NBLOCKS (NIMG * TILES * TILES)  // 12288

// exp(-(k-5)^2/4.5), unnormalized, symmetric. Double-accurate literals.
#define G0 0.0038659204f
#define G1 0.0285655010f
#define G2 0.1353352832f
#define G3 0.4111123050f
#define G4 0.8007374029f
#define G5 1.0f

__global__ __launch_bounds__(256, 5) void ssim_tile_kernel(
    const float* __restrict__ img1, const float* __restrict__ img2,
    float* __restrict__ partials)
{
    __shared__ float s1[PH][PWS];        // 7392 B
    __shared__ float s2[PH][PWS];        // 7392 B
    __shared__ float sh[3][TW][PWS];     // 16896 B, transposed [ch][col][row]
    __shared__ float s_part[4];

    const float gw[11] = {G0,G1,G2,G3,G4,G5,G4,G3,G2,G1,G0};

    const int tid = threadIdx.x;
    const int tx0 = blockIdx.x * TW - 5;
    const int ty0 = blockIdx.y * TH - 5;
    const float* __restrict__ p1 = img1 + (size_t)blockIdx.z * (IMG * IMG);
    const float* __restrict__ p2 = img2 + (size_t)blockIdx.z * (IMG * IMG);

    // ---- load 42x42 padded tiles (zero outside image) ----
#pragma unroll
    for (int it = 0; it < 7; ++it) {
        int i = tid + it * 256;
        if (i < PH * 42) {
            int r = i / 42, c = i - r * 42;
            int gr = ty0 + r, gc = tx0 + c;
            bool ok = ((unsigned)gr < IMG) && ((unsigned)gc < IMG);
            int gi = gr * IMG + gc;
            s1[r][c] = ok ? p1[gi] : 0.0f;
            s2[r][c] = ok ? p2[gi] : 0.0f;
        }
    }

    // h-pass task: 168 active threads, each = (row 0..41) x (8-col group 0..3)
    const bool hact = tid < 168;
    const int  hr  = hact ? (tid % 42) : 0;
    const int  hc0 = hact ? ((tid / 42) * 8) : 0;

    // v-pass mapping: 32 cols x 8 row-groups of 4
    const int col = tid & 31;
    const int r0  = (tid >> 5) * 4;

    __syncthreads();

    // ================= group 1: {mu1, x11} =================
    if (hact) {
        float v1[18];
        *(float4*)&v1[0]  = *(const float4*)&s1[hr][hc0 + 0];
        *(float4*)&v1[4]  = *(const float4*)&s1[hr][hc0 + 4];
        *(float4*)&v1[8]  = *(const float4*)&s1[hr][hc0 + 8];
        *(float4*)&v1[12] = *(const float4*)&s1[hr][hc0 + 12];
        *(float2*)&v1[16] = *(const float2*)&s1[hr][hc0 + 16];
        float m1[8], q11[8];
#pragma unroll
        for (int j = 0; j < 8; ++j) { m1[j] = 0.f; q11[j] = 0.f; }
#pragma unroll
        for (int k = 0; k < 11; ++k) {
            float w = gw[k];
#pragma unroll
            for (int j = 0; j < 8; ++j) {
                float a = v1[j + k];
                float t = w * a;
                m1[j] += t;
                q11[j] = fmaf(t, a, q11[j]);
            }
        }
#pragma unroll
        for (int j = 0; j < 8; ++j) {
            sh[0][hc0 + j][hr] = m1[j];
            sh[1][hc0 + j][hr] = q11[j];
        }
    }
    __syncthreads();

    float a_m1[4], a_q11[4];
    {
        float h[14];
#pragma unroll
        for (int ch = 0; ch < 2; ++ch) {
            const float* b = &sh[ch][col][0];
            *(float4*)&h[0]  = *(const float4*)&b[r0 + 0];
            *(float4*)&h[4]  = *(const float4*)&b[r0 + 4];
            *(float4*)&h[8]  = *(const float4*)&b[r0 + 8];
            *(float2*)&h[12] = *(const float2*)&b[r0 + 12];
            float* acc = ch ? a_q11 : a_m1;
#pragma unroll
            for (int i = 0; i < 4; ++i) {
                float s = 0.f;
#pragma unroll
                for (int k = 0; k < 11; ++k) s = fmaf(gw[k], h[i + k], s);
                acc[i] = s;
            }
        }
    }
    __syncthreads();   // sh about to be overwritten

    // ================= group 2: {mu2, x22, x12} =================
    if (hact) {
        float v1[18], v2[18];
        *(float4*)&v1[0]  = *(const float4*)&s1[hr][hc0 + 0];
        *(float4*)&v1[4]  = *(const float4*)&s1[hr][hc0 + 4];
        *(float4*)&v1[8]  = *(const float4*)&s1[hr][hc0 + 8];
        *(float4*)&v1[12] = *(const float4*)&s1[hr][hc0 + 12];
        *(float2*)&v1[16] = *(const float2*)&s1[hr][hc0 + 16];
        *(float4*)&v2[0]  = *(const float4*)&s2[hr][hc0 + 0];
        *(float4*)&v2[4]  = *(const float4*)&s2[hr][hc0 + 4];
        *(float4*)&v2[8]  = *(const float4*)&s2[hr][hc0 + 8];
        *(float4*)&v2[12] = *(const float4*)&s2[hr][hc0 + 12];
        *(float2*)&v2[16] = *(const float2*)&s2[hr][hc0 + 16];
        float m2[8], q22[8], q12[8];
#pragma unroll
        for (int j = 0; j < 8; ++j) { m2[j] = 0.f; q22[j] = 0.f; q12[j] = 0.f; }
#pragma unroll
        for (int k = 0; k < 11; ++k) {
            float w = gw[k];
#pragma unroll
            for (int j = 0; j < 8; ++j) {
                float b = v2[j + k];
                float t = w * b;
                m2[j] += t;
                q22[j] = fmaf(t, b, q22[j]);
                q12[j] = fmaf(t, v1[j + k], q12[j]);
            }
        }
#pragma unroll
        for (int j = 0; j < 8; ++j) {
            sh[0][hc0 + j][hr] = m2[j];
            sh[1][hc0 + j][hr] = q22[j];
            sh[2][hc0 + j][hr] = q12[j];
        }
    }
    __syncthreads();

    // v-pass group 2, per channel to limit live registers, then SSIM
    float a_m2[4], a_q22[4], a_q12[4];
    {
        float h[14];
#pragma unroll
        for (int ch = 0; ch < 3; ++ch) {
            const float* b = &sh[ch][col][0];
            *(float4*)&h[0]  = *(const float4*)&b[r0 + 0];
            *(float4*)&h[4]  = *(const float4*)&b[r0 + 4];
            *(float4*)&h[8]  = *(const float4*)&b[r0 + 8];
            *(float2*)&h[12] = *(const float2*)&b[r0 + 12];
            float* acc = (ch == 0) ? a_m2 : (ch == 1) ? a_q22 : a_q12;
#pragma unroll
            for (int i = 0; i < 4; ++i) {
                float s = 0.f;
#pragma unroll
                for (int k = 0; k < 11; ++k) s = fmaf(gw[k], h[i + k], s);
                acc[i] = s;
            }
        }
    }

    const float C1 = 1.0e-4f, C2 = 9.0e-4f;
    float local = 0.f;
#pragma unroll
    for (int i = 0; i < 4; ++i) {
        float mu1 = a_m1[i], mu2 = a_m2[i];
        float mu1s = mu1 * mu1, mu2s = mu2 * mu2, m12 = mu1 * mu2;
        float sg1 = a_q11[i] - mu1s, sg2 = a_q22[i] - mu2s, sg12 = a_q12[i] - m12;
        float num = (2.f * m12 + C1) * (2.f * sg12 + C2);
        float den = (mu1s + mu2s + C1) * (sg1 + sg2 + C2);
        local += num / den;
    }

#pragma unroll
    for (int off = 32; off > 0; off >>= 1)
        local += __shfl_down(local, off, 64);
    if ((tid & 63) == 0) s_part[tid >> 6] = local;
    __syncthreads();
    if (tid == 0) {
        int bidx = (blockIdx.z * gridDim.y + blockIdx.y) * gridDim.x + blockIdx.x;
        partials[bidx] = s_part[0] + s_part[1] + s_part[2] + s_part[3];
    }
}

__global__ __launch_bounds__(256) void ssim_final_kernel(
    const float* __restrict__ partials, float* __restrict__ out)
{
    __shared__ double sp[4];
    double acc = 0.0;
    for (int i = threadIdx.x; i < NBLOCKS; i += 256)
        acc += (double)partials[i];
#pragma unroll
    for (int off = 32; off > 0; off >>= 1)
        acc += __shfl_down(acc, off, 64);
    if ((threadIdx.x & 63) == 0) sp[threadIdx.x >> 6] = acc;
    __syncthreads();
    if (threadIdx.x == 0) {
        double total = sp[0] + sp[1] + sp[2] + sp[3];
        out[0] = (float)(1.0 - total / (double)((size_t)NIMG * IMG * IMG));
    }
}

extern "C" void kernel_launch(void* const* d_in, const int* in_sizes, int n_in,
                              void* d_out, int out_size, void* d_ws, size_t ws_size,
                              hipStream_t stream) {
    const float* img1 = (const float*)d_in[0];
    const float* img2 = (const float*)d_in[1];
    float* out = (float*)d_out;
    float* partials = (float*)d_ws;   // NBLOCKS floats, fully rewritten each call

    dim3 grid(TILES, TILES, NIMG);
    ssim_tile_kernel<<<grid, dim3(256), 0, stream>>>(img1, img2, partials);
    ssim_final_kernel<<<1, dim3(256), 0, stream>>>(partials, out);
}

// Round 3
// 189.297 us; speedup vs baseline: 1.1890x; 1.0560x over previous
//
#include <hip/hip_runtime.h>

// SSIM loss — fused separable-conv tile kernel, v3.
// vs v2: all LDS fragment reads are b128 (b64/float2 at stride%32==12 only
// covered 16 banks -> 2x conflict); stage loop div/mod -> incremental;
// fp32 div -> v_rcp (margin: absmax was 0.0, threshold 3.3e-5, fp64 final).

#define IMG   512
#define NIMG  48
#define TW    32
#define TH    32
#define PH    42          // TH + 10
#define PWS   44          // padded LDS row stride (42 used; 44%32=12 -> good b128 banking)
#define TILES 16
#define NBLOCKS (NIMG * TILES * TILES)  // 12288

// exp(-(k-5)^2/4.5), unnormalized, symmetric.
#define G0 0.0038659204f
#define G1 0.0285655010f
#define G2 0.1353352832f
#define G3 0.4111123050f
#define G4 0.8007374029f
#define G5 1.0f

__global__ __launch_bounds__(256, 5) void ssim_tile_kernel(
    const float* __restrict__ img1, const float* __restrict__ img2,
    float* __restrict__ partials)
{
    __shared__ float s1[PH][PWS];        // 7392 B
    __shared__ float s2[PH][PWS];        // 7392 B
    __shared__ float sh[3][TW][PWS];     // 16896 B, transposed [ch][col][row]
    __shared__ float s_part[4];

    const float gw[11] = {G0,G1,G2,G3,G4,G5,G4,G3,G2,G1,G0};

    const int tid = threadIdx.x;
    const int tx0 = blockIdx.x * TW - 5;
    const int ty0 = blockIdx.y * TH - 5;
    const float* __restrict__ p1 = img1 + (size_t)blockIdx.z * (IMG * IMG);
    const float* __restrict__ p2 = img2 + (size_t)blockIdx.z * (IMG * IMG);

    // ---- load 42x42 padded tiles; incremental row/col (256 = 6*42 + 4) ----
    {
        int r = tid / 42;
        int c = tid - r * 42;
#pragma unroll
        for (int it = 0; it < 7; ++it) {
            if (it < 6 || r < PH) {
                int gr = ty0 + r, gc = tx0 + c;
                bool ok = ((unsigned)gr < IMG) && ((unsigned)gc < IMG);
                int gi = gr * IMG + gc;
                s1[r][c] = ok ? p1[gi] : 0.0f;
                s2[r][c] = ok ? p2[gi] : 0.0f;
            }
            c += 4; r += 6;
            if (c >= 42) { c -= 42; r += 1; }
        }
    }

    // h-pass task: 168 active threads, each = (row 0..41) x (8-col group 0..3)
    const bool hact = tid < 168;
    const int  hr  = hact ? (tid % 42) : 0;
    const int  hc0 = hact ? ((tid / 42) * 8) : 0;

    // v-pass mapping: 32 cols x 8 row-groups of 4
    const int col = tid & 31;
    const int r0  = (tid >> 5) * 4;

    __syncthreads();

    // ================= group 1: {mu1, x11} =================
    if (hact) {
        float v1[20];
#pragma unroll
        for (int q = 0; q < 5; ++q)
            *(float4*)&v1[4 * q] = *(const float4*)&s1[hr][hc0 + 4 * q];
        float m1[8], q11[8];
#pragma unroll
        for (int j = 0; j < 8; ++j) { m1[j] = 0.f; q11[j] = 0.f; }
#pragma unroll
        for (int k = 0; k < 11; ++k) {
            float w = gw[k];
#pragma unroll
            for (int j = 0; j < 8; ++j) {
                float a = v1[j + k];
                float t = w * a;
                m1[j] += t;
                q11[j] = fmaf(t, a, q11[j]);
            }
        }
#pragma unroll
        for (int j = 0; j < 8; ++j) {
            sh[0][hc0 + j][hr] = m1[j];
            sh[1][hc0 + j][hr] = q11[j];
        }
    }
    __syncthreads();

    float a_m1[4], a_q11[4];
    {
        float h[16];
#pragma unroll
        for (int ch = 0; ch < 2; ++ch) {
            const float* b = &sh[ch][col][0];
#pragma unroll
            for (int q = 0; q < 4; ++q)
                *(float4*)&h[4 * q] = *(const float4*)&b[r0 + 4 * q];
            float* acc = ch ? a_q11 : a_m1;
#pragma unroll
            for (int i = 0; i < 4; ++i) {
                float s = 0.f;
#pragma unroll
                for (int k = 0; k < 11; ++k) s = fmaf(gw[k], h[i + k], s);
                acc[i] = s;
            }
        }
    }
    __syncthreads();   // sh about to be overwritten

    // ================= group 2: {mu2, x22, x12} =================
    if (hact) {
        float v1[20], v2[20];
#pragma unroll
        for (int q = 0; q < 5; ++q) {
            *(float4*)&v1[4 * q] = *(const float4*)&s1[hr][hc0 + 4 * q];
            *(float4*)&v2[4 * q] = *(const float4*)&s2[hr][hc0 + 4 * q];
        }
        float m2[8], q22[8], q12[8];
#pragma unroll
        for (int j = 0; j < 8; ++j) { m2[j] = 0.f; q22[j] = 0.f; q12[j] = 0.f; }
#pragma unroll
        for (int k = 0; k < 11; ++k) {
            float w = gw[k];
#pragma unroll
            for (int j = 0; j < 8; ++j) {
                float b = v2[j + k];
                float t = w * b;
                m2[j] += t;
                q22[j] = fmaf(t, b, q22[j]);
                q12[j] = fmaf(t, v1[j + k], q12[j]);
            }
        }
#pragma unroll
        for (int j = 0; j < 8; ++j) {
            sh[0][hc0 + j][hr] = m2[j];
            sh[1][hc0 + j][hr] = q22[j];
            sh[2][hc0 + j][hr] = q12[j];
        }
    }
    __syncthreads();

    // v-pass group 2, per channel, then SSIM
    float a_m2[4], a_q22[4], a_q12[4];
    {
        float h[16];
#pragma unroll
        for (int ch = 0; ch < 3; ++ch) {
            const float* b = &sh[ch][col][0];
#pragma unroll
            for (int q = 0; q < 4; ++q)
                *(float4*)&h[4 * q] = *(const float4*)&b[r0 + 4 * q];
            float* acc = (ch == 0) ? a_m2 : (ch == 1) ? a_q22 : a_q12;
#pragma unroll
            for (int i = 0; i < 4; ++i) {
                float s = 0.f;
#pragma unroll
                for (int k = 0; k < 11; ++k) s = fmaf(gw[k], h[i + k], s);
                acc[i] = s;
            }
        }
    }

    const float C1 = 1.0e-4f, C2 = 9.0e-4f;
    float local = 0.f;
#pragma unroll
    for (int i = 0; i < 4; ++i) {
        float mu1 = a_m1[i], mu2 = a_m2[i];
        float mu1s = mu1 * mu1, mu2s = mu2 * mu2, m12 = mu1 * mu2;
        float sg1 = a_q11[i] - mu1s, sg2 = a_q22[i] - mu2s, sg12 = a_q12[i] - m12;
        float num = (2.f * m12 + C1) * (2.f * sg12 + C2);
        float den = (mu1s + mu2s + C1) * (sg1 + sg2 + C2);
        // v_rcp + mul: ~1e-7 rel err; absmax was 0.0 vs 3.3e-5 threshold,
        // and the cross-block reduce is fp64 — ample margin.
        local = fmaf(num, __builtin_amdgcn_rcpf(den), local);
    }

#pragma unroll
    for (int off = 32; off > 0; off >>= 1)
        local += __shfl_down(local, off, 64);
    if ((tid & 63) == 0) s_part[tid >> 6] = local;
    __syncthreads();
    if (tid == 0) {
        int bidx = (blockIdx.z * gridDim.y + blockIdx.y) * gridDim.x + blockIdx.x;
        partials[bidx] = s_part[0] + s_part[1] + s_part[2] + s_part[3];
    }
}

__global__ __launch_bounds__(256) void ssim_final_kernel(
    const float* __restrict__ partials, float* __restrict__ out)
{
    __shared__ double sp[4];
    double acc = 0.0;
    for (int i = threadIdx.x; i < NBLOCKS; i += 256)
        acc += (double)partials[i];
#pragma unroll
    for (int off = 32; off > 0; off >>= 1)
        acc += __shfl_down(acc, off, 64);
    if ((threadIdx.x & 63) == 0) sp[threadIdx.x >> 6] = acc;
    __syncthreads();
    if (threadIdx.x == 0) {
        double total = sp[0] + sp[1] + sp[2] + sp[3];
        out[0] = (float)(1.0 - total / (double)((size_t)NIMG * IMG * IMG));
    }
}

extern "C" void kernel_launch(void* const* d_in, const int* in_sizes, int n_in,
                              void* d_out, int out_size, void* d_ws, size_t ws_size,
                              hipStream_t stream) {
    const float* img1 = (const float*)d_in[0];
    const float* img2 = (const float*)d_in[1];
    float* out = (float*)d_out;
    float* partials = (float*)d_ws;   // NBLOCKS floats, fully rewritten each call

    dim3 grid(TILES, TILES, NIMG);
    ssim_tile_kernel<<<grid, dim3(256), 0, stream>>>(img1, img2, partials);
    ssim_final_kernel<<<1, dim3(256), 0, stream>>>(partials, out);
}

// Round 4
// 165.345 us; speedup vs baseline: 1.3612x; 1.1449x over previous
//
#include <hip/hip_runtime.h>

// SSIM loss — fused separable-conv tile kernel, v4.
// vs v3: algebraic 4-channel form. SSIM only needs sigma1+sigma2 (sum), so
// stage s=v1+v2, d=v1-v2 and conv {mu_s, x_ss, mu_d, x_dd}:
//   mu1^2+mu2^2=(ms^2+md^2)/2, mu1*mu2=(ms^2-md^2)/4,
//   x11+x22=(xss+xdd)/2, x12=(xss-xdd)/4.
// -> 14-20% less conv math, 33% fewer h-pass LDS reads, sh shrinks to 2
// channels -> 26.1 KB LDS -> 6 blocks/CU. Interior blocks skip bounds checks.

#define IMG   512
#define NIMG  48
#define TW    32
#define TH    32
#define PH    42          // TH + 10
#define PWS   44          // padded LDS row stride
#define TILES 16
#define NBLOCKS (NIMG * TILES * TILES)  // 12288

// exp(-(k-5)^2/4.5), unnormalized, symmetric.
#define G0 0.0038659204f
#define G1 0.0285655010f
#define G2 0.1353352832f
#define G3 0.4111123050f
#define G4 0.8007374029f
#define G5 1.0f

__global__ __launch_bounds__(256, 6) void ssim_tile_kernel(
    const float* __restrict__ img1, const float* __restrict__ img2,
    float* __restrict__ partials)
{
    __shared__ float ssm[PH][PWS];       // s = v1+v2   (7392 B)
    __shared__ float sdf[PH][PWS];       // d = v1-v2   (7392 B)
    __shared__ float sh[2][TW][PWS];     // transposed [ch][col][row] (11264 B)
    __shared__ float s_part[4];

    const float gw[11] = {G0,G1,G2,G3,G4,G5,G4,G3,G2,G1,G0};

    const int tid = threadIdx.x;
    const int tx0 = blockIdx.x * TW - 5;
    const int ty0 = blockIdx.y * TH - 5;
    const float* __restrict__ p1 = img1 + (size_t)blockIdx.z * (IMG * IMG);
    const float* __restrict__ p2 = img2 + (size_t)blockIdx.z * (IMG * IMG);

    // ---- stage 42x42 of s,d; incremental row/col (256 = 6*42 + 4) ----
    {
        const bool interior = (blockIdx.x >= 1) && (blockIdx.x <= TILES - 2) &&
                              (blockIdx.y >= 1) && (blockIdx.y <= TILES - 2);
        int r = tid / 42;
        int c = tid - r * 42;
        if (interior) {
#pragma unroll
            for (int it = 0; it < 7; ++it) {
                if (it < 6 || r < PH) {
                    int gi = (ty0 + r) * IMG + (tx0 + c);
                    float a = p1[gi], b = p2[gi];
                    ssm[r][c] = a + b;
                    sdf[r][c] = a - b;
                }
                c += 4; r += 6;
                if (c >= 42) { c -= 42; r += 1; }
            }
        } else {
#pragma unroll
            for (int it = 0; it < 7; ++it) {
                if (it < 6 || r < PH) {
                    int gr = ty0 + r, gc = tx0 + c;
                    bool ok = ((unsigned)gr < IMG) && ((unsigned)gc < IMG);
                    int gi = gr * IMG + gc;
                    float a = ok ? p1[gi] : 0.0f;
                    float b = ok ? p2[gi] : 0.0f;
                    ssm[r][c] = a + b;
                    sdf[r][c] = a - b;
                }
                c += 4; r += 6;
                if (c >= 42) { c -= 42; r += 1; }
            }
        }
    }

    // h-pass task: 168 active threads, each = (row 0..41) x (8-col group 0..3)
    const bool hact = tid < 168;
    const int  hr  = hact ? (tid % 42) : 0;
    const int  hc0 = hact ? ((tid / 42) * 8) : 0;

    // v-pass mapping: 32 cols x 8 row-groups of 4
    const int col = tid & 31;
    const int r0  = (tid >> 5) * 4;

    float a_ms[4], a_xss[4], a_md[4], a_xdd[4];

    __syncthreads();

    // ================= group A: s -> {mu_s, x_ss} =================
    if (hact) {
        float v[20];
#pragma unroll
        for (int q = 0; q < 5; ++q)
            *(float4*)&v[4 * q] = *(const float4*)&ssm[hr][hc0 + 4 * q];
        float m[8], x[8];
#pragma unroll
        for (int j = 0; j < 8; ++j) { m[j] = 0.f; x[j] = 0.f; }
#pragma unroll
        for (int k = 0; k < 11; ++k) {
            float w = gw[k];
#pragma unroll
            for (int j = 0; j < 8; ++j) {
                float a = v[j + k];
                float t = w * a;
                m[j] += t;
                x[j] = fmaf(t, a, x[j]);
            }
        }
        float* sb = &sh[0][hc0][hr];     // ch stride 1408 floats, col stride 44
#pragma unroll
        for (int j = 0; j < 8; ++j) {
            sb[j * PWS] = m[j];
            sb[TW * PWS + j * PWS] = x[j];
        }
    }
    __syncthreads();

    {
        const float* vb = &sh[0][col][r0];
        float h[16];
#pragma unroll
        for (int q = 0; q < 4; ++q)
            *(float4*)&h[4 * q] = *(const float4*)&vb[4 * q];
#pragma unroll
        for (int i = 0; i < 4; ++i) {
            float s = 0.f;
#pragma unroll
            for (int k = 0; k < 11; ++k) s = fmaf(gw[k], h[i + k], s);
            a_ms[i] = s;
        }
#pragma unroll
        for (int q = 0; q < 4; ++q)
            *(float4*)&h[4 * q] = *(const float4*)&vb[TW * PWS + 4 * q];
#pragma unroll
        for (int i = 0; i < 4; ++i) {
            float s = 0.f;
#pragma unroll
            for (int k = 0; k < 11; ++k) s = fmaf(gw[k], h[i + k], s);
            a_xss[i] = s;
        }
    }
    __syncthreads();   // sh about to be overwritten

    // ================= group B: d -> {mu_d, x_dd} =================
    if (hact) {
        float v[20];
#pragma unroll
        for (int q = 0; q < 5; ++q)
            *(float4*)&v[4 * q] = *(const float4*)&sdf[hr][hc0 + 4 * q];
        float m[8], x[8];
#pragma unroll
        for (int j = 0; j < 8; ++j) { m[j] = 0.f; x[j] = 0.f; }
#pragma unroll
        for (int k = 0; k < 11; ++k) {
            float w = gw[k];
#pragma unroll
            for (int j = 0; j < 8; ++j) {
                float a = v[j + k];
                float t = w * a;
                m[j] += t;
                x[j] = fmaf(t, a, x[j]);
            }
        }
        float* sb = &sh[0][hc0][hr];
#pragma unroll
        for (int j = 0; j < 8; ++j) {
            sb[j * PWS] = m[j];
            sb[TW * PWS + j * PWS] = x[j];
        }
    }
    __syncthreads();

    {
        const float* vb = &sh[0][col][r0];
        float h[16];
#pragma unroll
        for (int q = 0; q < 4; ++q)
            *(float4*)&h[4 * q] = *(const float4*)&vb[4 * q];
#pragma unroll
        for (int i = 0; i < 4; ++i) {
            float s = 0.f;
#pragma unroll
            for (int k = 0; k < 11; ++k) s = fmaf(gw[k], h[i + k], s);
            a_md[i] = s;
        }
#pragma unroll
        for (int q = 0; q < 4; ++q)
            *(float4*)&h[4 * q] = *(const float4*)&vb[TW * PWS + 4 * q];
#pragma unroll
        for (int i = 0; i < 4; ++i) {
            float s = 0.f;
#pragma unroll
            for (int k = 0; k < 11; ++k) s = fmaf(gw[k], h[i + k], s);
            a_xdd[i] = s;
        }
    }

    // ---- SSIM from 4-channel algebra ----
    const float C1 = 1.0e-4f, C2 = 9.0e-4f;
    float local = 0.f;
#pragma unroll
    for (int i = 0; i < 4; ++i) {
        float ms = a_ms[i], md = a_md[i];
        float xss = a_xss[i], xdd = a_xdd[i];
        float ms2 = ms * ms, md2 = md * md;
        float sum2 = 0.5f * (ms2 + md2);    // mu1^2 + mu2^2
        float m12  = 0.25f * (ms2 - md2);   // mu1 * mu2
        float xsum = 0.5f * (xss + xdd);    // x11 + x22
        float x12  = 0.25f * (xss - xdd);
        float sg12 = x12 - m12;
        float sgsum = xsum - sum2;          // sigma1_sq + sigma2_sq
        float num = (2.f * m12 + C1) * (2.f * sg12 + C2);
        float den = (sum2 + C1) * (sgsum + C2);
        local = fmaf(num, __builtin_amdgcn_rcpf(den), local);
    }

#pragma unroll
    for (int off = 32; off > 0; off >>= 1)
        local += __shfl_down(local, off, 64);
    if ((tid & 63) == 0) s_part[tid >> 6] = local;
    __syncthreads();
    if (tid == 0) {
        int bidx = (blockIdx.z * gridDim.y + blockIdx.y) * gridDim.x + blockIdx.x;
        partials[bidx] = s_part[0] + s_part[1] + s_part[2] + s_part[3];
    }
}

__global__ __launch_bounds__(256) void ssim_final_kernel(
    const float* __restrict__ partials, float* __restrict__ out)
{
    __shared__ double sp[4];
    double acc = 0.0;
    for (int i = threadIdx.x; i < NBLOCKS; i += 256)
        acc += (double)partials[i];
#pragma unroll
    for (int off = 32; off > 0; off >>= 1)
        acc += __shfl_down(acc, off, 64);
    if ((threadIdx.x & 63) == 0) sp[threadIdx.x >> 6] = acc;
    __syncthreads();
    if (threadIdx.x == 0) {
        double total = sp[0] + sp[1] + sp[2] + sp[3];
        out[0] = (float)(1.0 - total / (double)((size_t)NIMG * IMG * IMG));
    }
}

extern "C" void kernel_launch(void* const* d_in, const int* in_sizes, int n_in,
                              void* d_out, int out_size, void* d_ws, size_t ws_size,
                              hipStream_t stream) {
    const float* img1 = (const float*)d_in[0];
    const float* img2 = (const float*)d_in[1];
    float* out = (float*)d_out;
    float* partials = (float*)d_ws;   // NBLOCKS floats, fully rewritten each call

    dim3 grid(TILES, TILES, NIMG);
    ssim_tile_kernel<<<grid, dim3(256), 0, stream>>>(img1, img2, partials);
    ssim_final_kernel<<<1, dim3(256), 0, stream>>>(partials, out);
}